// Round 5
// baseline (177.042 us; speedup 1.0000x reference)
//
#include <hip/hip_runtime.h>
#include <stdint.h>

#define S_LEN 4096
#define DMOD  768
#define NH    12
#define DH    64
#define GG    32
#define NEGBIG (-1e9f)

typedef _Float16 f16;
typedef f16 f16x8 __attribute__((ext_vector_type(8)));
typedef f16 f16x4 __attribute__((ext_vector_type(4)));
typedef float f32x4 __attribute__((ext_vector_type(4)));
typedef uint32_t u32;

// ---------- workspace offsets (bytes), all 256-aligned ----------
#define OFF_H16   ((size_t)0)
#define OFF_WT    ((size_t)6291456)
#define OFF_Q     ((size_t)11010048)
#define OFF_K     ((size_t)17301504)
#define OFF_VT    ((size_t)29884416)
#define OFF_ATT   ((size_t)36175872)
#define OFF_GQO   ((size_t)42467328)
#define OFF_GQL   ((size_t)44040192)

__device__ __forceinline__ void gld_lds16(const void* g, void* l) {
  typedef __attribute__((address_space(3))) u32 lds_u32;
  typedef __attribute__((address_space(1))) u32 glb_u32;
  __builtin_amdgcn_global_load_lds((glb_u32*)(uintptr_t)g,
                                   (lds_u32*)(u32)(uintptr_t)l, 16, 0, 0);
}

// ---------------- prep: weight transpose->f16 + hidden convert ----------------
__global__ __launch_bounds__(256) void prep_kernel(
    const float* __restrict__ hs,
    const float* __restrict__ Wq, const float* __restrict__ Wk,
    const float* __restrict__ Wv, const float* __restrict__ Wo,
    f16* __restrict__ h16, f16* __restrict__ wt)
{
  const int b = blockIdx.x;
  const int t = threadIdx.x;
  if (b < 576) {
    __shared__ float tile[64][65];
    const int w = b / 144, r2 = b % 144;
    const int n0 = (r2 % 12) * 64, k0 = (r2 / 12) * 64;
    const float* W = (w==0) ? Wq : (w==1) ? Wk : (w==2) ? Wv : Wo;
    f16* WT = wt + (size_t)w * DMOD * DMOD;
    #pragma unroll
    for (int rnd = 0; rnd < 4; ++rnd) {
      const int lin = rnd * 1024 + t * 4;
      const int r = lin >> 6, c = lin & 63;
      const float4 vv = *(const float4*)(W + (size_t)(k0 + r) * DMOD + n0 + c);
      tile[r][c+0] = vv.x; tile[r][c+1] = vv.y; tile[r][c+2] = vv.z; tile[r][c+3] = vv.w;
    }
    __syncthreads();
    #pragma unroll
    for (int rnd = 0; rnd < 2; ++rnd) {
      const int lin = rnd * 256 + t;
      const int n = lin >> 3, kc = (lin & 7) * 8;
      f16x8 o;
      #pragma unroll
      for (int j = 0; j < 8; ++j) o[j] = (f16)tile[kc + j][n];
      *(f16x8*)(WT + (size_t)(n0 + n) * DMOD + k0 + kc) = o;
    }
  } else {
    const size_t idx = (size_t)(b - 576) * 2048 + (size_t)t * 8;
    const float4 a = *(const float4*)(hs + idx);
    const float4 c = *(const float4*)(hs + idx + 4);
    f16x8 o;
    o[0]=(f16)a.x; o[1]=(f16)a.y; o[2]=(f16)a.z; o[3]=(f16)a.w;
    o[4]=(f16)c.x; o[5]=(f16)c.y; o[6]=(f16)c.z; o[7]=(f16)c.w;
    *(f16x8*)(h16 + idx) = o;
  }
}

// ---------------- QKV projection GEMM: 64Mx128N tiles, depth-2 prefetch ----------------
// 1152 blocks (4.5/CU), 36KB LDS (4/CU cap). Per iter: wait vmcnt(3) [FIFO =>
// buf k landed], s_barrier, issue buf[(k+2)%3] AFTER barrier (all waves done
// reading it: last read was compute k-1), compute buf[k%3].
// z==2 (v) writes directly transposed (H,64,S): acc rows are 4 consecutive s.
__global__ __launch_bounds__(256) void gemm_qkv(
    const f16* __restrict__ A, const f16* __restrict__ wt,
    const float* __restrict__ bq, const float* __restrict__ bk, const float* __restrict__ bv,
    f16* __restrict__ q16, f16* __restrict__ k16, f16* __restrict__ vt16)
{
  __shared__ __align__(16) f16 At[3][2048];
  __shared__ __align__(16) f16 Bt[3][4096];
  const int z = blockIdx.z;
  const f16* Wt = wt + (size_t)z * DMOD * DMOD;
  const float* bias = (z==0) ? bq : (z==1) ? bk : bv;
  const float scale = (z==0) ? 0.125f : 1.0f;

  const int tid = threadIdx.x;
  const int lane = tid & 63, wid = tid >> 6;
  const int quad = lane >> 4, l15 = lane & 15;
  const int n0 = blockIdx.x * 128, m0 = blockIdx.y * 64;
  const int wm = (wid >> 1) * 32, wn = (wid & 1) * 64;

  f32x4 acc[2][4];
  #pragma unroll
  for (int i=0;i<2;++i)
    #pragma unroll
    for (int j=0;j<4;++j) acc[i][j] = (f32x4){0.f,0.f,0.f,0.f};

  // staging maps: At chunk t (t<256), Bt chunks t and t+256
  const int arA = ((tid>>6)<<4) + (tid&15), acA = ((tid>>4)&3)*8;
  const int b0 = tid, b1 = tid + 256;
  const int arB0 = ((b0>>6)<<4) + (b0&15), acB0 = ((b0>>4)&3)*8;
  const int arB1 = ((b1>>6)<<4) + (b1&15), acB1 = ((b1>>4)&3)*8;
  const f16* Ab = A  + (size_t)m0 * DMOD;
  const f16* Bb = Wt + (size_t)n0 * DMOD;

  // prologue: stage k-chunks 0,1 into buffers 0,1 (3 loads each per thread)
  #pragma unroll
  for (int p = 0; p < 2; ++p) {
    const int k0 = p * 32;
    gld_lds16(Ab + (size_t)arA*DMOD  + k0 + acA,  &At[p][tid*8]);
    gld_lds16(Bb + (size_t)arB0*DMOD + k0 + acB0, &Bt[p][b0*8]);
    gld_lds16(Bb + (size_t)arB1*DMOD + k0 + acB1, &Bt[p][b1*8]);
  }

  #pragma unroll 3
  for (int k = 0; k < 24; ++k) {
    const int cb = k % 3, ib = (k + 2) % 3;
    if (k < 23) {
      asm volatile("s_waitcnt vmcnt(3) lgkmcnt(0)" ::: "memory");
    } else {
      asm volatile("s_waitcnt vmcnt(0) lgkmcnt(0)" ::: "memory");
    }
    __builtin_amdgcn_s_barrier();
    if (k < 22) {
      const int k0 = (k + 2) * 32;
      gld_lds16(Ab + (size_t)arA*DMOD  + k0 + acA,  &At[ib][tid*8]);
      gld_lds16(Bb + (size_t)arB0*DMOD + k0 + acB0, &Bt[ib][b0*8]);
      gld_lds16(Bb + (size_t)arB1*DMOD + k0 + acB1, &Bt[ib][b1*8]);
    }
    f16x8 af[2], bf[4];
    #pragma unroll
    for (int i=0;i<2;++i)
      af[i] = *(const f16x8*)(&At[cb][((wm>>4)+i)*512 + lane*8]);
    #pragma unroll
    for (int j=0;j<4;++j)
      bf[j] = *(const f16x8*)(&Bt[cb][((wn>>4)+j)*512 + lane*8]);
    #pragma unroll
    for (int i=0;i<2;++i)
      #pragma unroll
      for (int j=0;j<4;++j)
        acc[i][j] = __builtin_amdgcn_mfma_f32_16x16x32_f16(af[i], bf[j], acc[i][j], 0, 0, 0);
  }

  if (z < 2) {
    f16* outp = (z==0) ? q16 : k16;
    #pragma unroll
    for (int j=0;j<4;++j) {
      const int col = n0 + wn + j*16 + l15;
      const float bcol = bias[col];
      const int h = col >> 6, d = col & 63;
      #pragma unroll
      for (int i=0;i<2;++i) {
        const int rbase = m0 + wm + i*16 + quad*4;
        f16* dst = outp + ((size_t)h * S_LEN + rbase) * DH + d;
        #pragma unroll
        for (int r=0;r<4;++r)
          dst[(size_t)r * DH] = (f16)((acc[i][j][r] + bcol) * scale);
      }
    }
  } else {
    #pragma unroll
    for (int j=0;j<4;++j) {
      const int col = n0 + wn + j*16 + l15;
      const float bcol = bias[col];
      const int h = col >> 6, d = col & 63;
      #pragma unroll
      for (int i=0;i<2;++i) {
        const int rbase = m0 + wm + i*16 + quad*4;
        f16x4 o;
        #pragma unroll
        for (int r=0;r<4;++r) o[r] = (f16)(acc[i][j][r] + bcol);
        *(f16x4*)(vt16 + ((size_t)h * DH + d) * S_LEN + rbase) = o;
      }
    }
  }
}

// ---------------- output GEMM: 64Mx64N tiles, depth-2 prefetch ----------------
// 768 blocks (3/CU), 24KB LDS. Same pipeline discipline as gemm_qkv.
__global__ __launch_bounds__(256) void gemm_out(
    const f16* __restrict__ A, const f16* __restrict__ Wt,
    const float* __restrict__ bo, float* __restrict__ outp)
{
  __shared__ __align__(16) f16 At[3][2048];
  __shared__ __align__(16) f16 Bt[3][2048];
  const int tid = threadIdx.x;
  const int lane = tid & 63, wid = tid >> 6;
  const int quad = lane >> 4, l15 = lane & 15;
  const int n0 = blockIdx.x * 64, m0 = blockIdx.y * 64;
  const int wm = (wid >> 1) * 32, wn = (wid & 1) * 32;

  f32x4 acc[2][2];
  #pragma unroll
  for (int i=0;i<2;++i)
    #pragma unroll
    for (int j=0;j<2;++j) acc[i][j] = (f32x4){0.f,0.f,0.f,0.f};

  const int ar = ((tid>>6)<<4) + (tid&15), ac = ((tid>>4)&3)*8;
  const f16* Ab = A  + (size_t)m0 * DMOD;
  const f16* Bb = Wt + (size_t)n0 * DMOD;

  #pragma unroll
  for (int p = 0; p < 2; ++p) {
    const int k0 = p * 32;
    gld_lds16(Ab + (size_t)ar*DMOD + k0 + ac, &At[p][tid*8]);
    gld_lds16(Bb + (size_t)ar*DMOD + k0 + ac, &Bt[p][tid*8]);
  }

  #pragma unroll 3
  for (int k = 0; k < 24; ++k) {
    const int cb = k % 3, ib = (k + 2) % 3;
    if (k < 23) {
      asm volatile("s_waitcnt vmcnt(2) lgkmcnt(0)" ::: "memory");
    } else {
      asm volatile("s_waitcnt vmcnt(0) lgkmcnt(0)" ::: "memory");
    }
    __builtin_amdgcn_s_barrier();
    if (k < 22) {
      const int k0 = (k + 2) * 32;
      gld_lds16(Ab + (size_t)ar*DMOD + k0 + ac, &At[ib][tid*8]);
      gld_lds16(Bb + (size_t)ar*DMOD + k0 + ac, &Bt[ib][tid*8]);
    }
    f16x8 af[2], bf[2];
    #pragma unroll
    for (int i=0;i<2;++i) {
      af[i] = *(const f16x8*)(&At[cb][((wm>>4)+i)*512 + lane*8]);
      bf[i] = *(const f16x8*)(&Bt[cb][((wn>>4)+i)*512 + lane*8]);
    }
    #pragma unroll
    for (int i=0;i<2;++i)
      #pragma unroll
      for (int j=0;j<2;++j)
        acc[i][j] = __builtin_amdgcn_mfma_f32_16x16x32_f16(af[i], bf[j], acc[i][j], 0, 0, 0);
  }

  #pragma unroll
  for (int j=0;j<2;++j) {
    const int col = n0 + wn + j*16 + l15;
    const float bcol = bo[col];
    #pragma unroll
    for (int i=0;i<2;++i) {
      const int rbase = m0 + wm + i*16 + quad*4;
      #pragma unroll
      for (int r=0;r<4;++r)
        outp[(size_t)(rbase + r) * DMOD + col] = acc[i][j][r] + bcol;
    }
  }
}

// ---------------- banded attention + global-query partials, one WAVE per job ----------------
__global__ __launch_bounds__(256) void band_attn(
    const f16* __restrict__ q16, const f16* __restrict__ k16,
    const f16* __restrict__ vt16, f16* __restrict__ att16,
    float* __restrict__ o_part, float* __restrict__ l_part)
{
  __shared__ __align__(16) f16 Pbuf[4][1280];  // 32x40 f16 per wave
  const int h = blockIdx.y;
  const int tid = threadIdx.x, lane = tid & 63, wid = tid >> 6;
  const int quad = lane >> 4, l15 = lane & 15;
  f16* P = &Pbuf[wid][0];

  const int bx = blockIdx.x;
  const bool is_gq = (bx >= 32);
  int gr0 = 0, sp = 0, tcount;
  if (is_gq) {
    sp = (bx - 32) * 4 + wid;
    tcount = 8;
  } else {
    const int sub = bx * 4 + wid;
    if (sub == 0) return;                      // rows 0..31 handled by gq path
    gr0 = sub * 32;
    tcount = 10;
  }

  const f16* qh = q16 + (size_t)h * S_LEN * DH;
  const f16* kh = k16 + (size_t)h * S_LEN * DH;
  const f16* vh = vt16 + (size_t)h * DH * S_LEN;

  f16x8 aq[2][2];
  #pragma unroll
  for (int mt=0;mt<2;++mt)
    #pragma unroll
    for (int ks=0;ks<2;++ks)
      aq[mt][ks] = *(const f16x8*)(qh + (size_t)(gr0 + mt*16 + l15)*DH + ks*32 + quad*8);

  f32x4 accO[2][4];
  float lacc[2][4];
  #pragma unroll
  for (int mt=0;mt<2;++mt) {
    #pragma unroll
    for (int n=0;n<4;++n) accO[mt][n] = (f32x4){0.f,0.f,0.f,0.f};
    #pragma unroll
    for (int r=0;r<4;++r) lacc[mt][r] = 0.f;
  }

  for (int t = 0; t < tcount; ++t) {
    int j0;
    if (is_gq) {
      j0 = sp*256 + t*32;
    } else if (t > 0) {
      j0 = gr0 - 128 + (t-1)*32;
      if (j0 <= 0 || j0 >= S_LEN) continue;    // whole-tile j-clip (always aligned)
    } else {
      j0 = 0;                                  // 32 global key columns
    }
    f16x8 bk[2][2];
    #pragma unroll
    for (int nt=0;nt<2;++nt) {
      const int key = j0 + nt*16 + l15;
      #pragma unroll
      for (int ks=0;ks<2;++ks)
        bk[nt][ks] = *(const f16x8*)(kh + (size_t)key*DH + ks*32 + quad*8);
    }
    f32x4 sc[2][2];
    #pragma unroll
    for (int mt=0;mt<2;++mt)
      #pragma unroll
      for (int nt=0;nt<2;++nt) {
        f32x4 s = __builtin_amdgcn_mfma_f32_16x16x32_f16(aq[mt][0], bk[nt][0],
                                                         (f32x4){0.f,0.f,0.f,0.f}, 0,0,0);
        sc[mt][nt] = __builtin_amdgcn_mfma_f32_16x16x32_f16(aq[mt][1], bk[nt][1], s, 0,0,0);
      }
    if (!is_gq && (t == 1 || t == 9)) {        // only edge band tiles need masks
      #pragma unroll
      for (int nt=0;nt<2;++nt)
        #pragma unroll
        for (int mt=0;mt<2;++mt)
          #pragma unroll
          for (int r=0;r<4;++r) {
            const int e = (nt*16 + l15) - (mt*16 + quad*4 + r);
            const bool ok = (t == 1) ? (e >= 0) : (e <= 0);
            if (!ok) sc[mt][nt][r] = NEGBIG;
          }
    }
    #pragma unroll
    for (int mt=0;mt<2;++mt)
      #pragma unroll
      for (int r=0;r<4;++r) {
        sc[mt][0][r] = __expf(sc[mt][0][r]);
        sc[mt][1][r] = __expf(sc[mt][1][r]);
        lacc[mt][r] += sc[mt][0][r] + sc[mt][1][r];
      }
    // P: C-layout -> LDS -> A-layout (per-wave scratch; in-order DS queue)
    #pragma unroll
    for (int mt=0;mt<2;++mt)
      #pragma unroll
      for (int nt=0;nt<2;++nt)
        #pragma unroll
        for (int r=0;r<4;++r)
          P[(mt*16 + quad*4 + r)*40 + nt*16 + l15] = (f16)sc[mt][nt][r];
    asm volatile("s_waitcnt lgkmcnt(0)" ::: "memory");
    f16x8 ap[2];
    #pragma unroll
    for (int mt=0;mt<2;++mt)
      ap[mt] = *(const f16x8*)(P + (mt*16 + l15)*40 + quad*8);
    #pragma unroll
    for (int n=0;n<4;++n) {
      const f16x8 bv = *(const f16x8*)(vh + (size_t)(n*16 + l15)*S_LEN + j0 + quad*8);
      #pragma unroll
      for (int mt=0;mt<2;++mt)
        accO[mt][n] = __builtin_amdgcn_mfma_f32_16x16x32_f16(ap[mt], bv, accO[mt][n], 0,0,0);
    }
  }

  // in-wave reduce of l partials across the 16 column-lanes
  #pragma unroll
  for (int mt=0;mt<2;++mt)
    #pragma unroll
    for (int r=0;r<4;++r) {
      float v = lacc[mt][r];
      v += __shfl_xor(v, 1, 64);
      v += __shfl_xor(v, 2, 64);
      v += __shfl_xor(v, 4, 64);
      v += __shfl_xor(v, 8, 64);
      lacc[mt][r] = v;
    }

  if (is_gq) {
    const int base = (h*16 + sp)*32;
    #pragma unroll
    for (int mt=0;mt<2;++mt)
      #pragma unroll
      for (int r=0;r<4;++r) {
        const int row = mt*16 + quad*4 + r;
        if (l15 == 0) l_part[base+row] = lacc[mt][r];
        #pragma unroll
        for (int n=0;n<4;++n)
          o_part[(size_t)(base+row)*DH + n*16 + l15] = accO[mt][n][r];
      }
  } else {
    #pragma unroll
    for (int mt=0;mt<2;++mt)
      #pragma unroll
      for (int r=0;r<4;++r) {
        const float inv = 1.f / lacc[mt][r];
        const int s = gr0 + mt*16 + quad*4 + r;
        #pragma unroll
        for (int n=0;n<4;++n)
          att16[(size_t)s * DMOD + h*DH + n*16 + l15] = (f16)(accO[mt][n][r] * inv);
      }
  }
}

__global__ __launch_bounds__(256) void gq_merge(
    const float* __restrict__ o_part, const float* __restrict__ l_part,
    f16* __restrict__ att16)
{
  const int h = blockIdx.x;
  const int t = threadIdx.x;
  for (int u = t; u < 512; u += 256) {
    const int row = u >> 4, c4 = u & 15;
    float4 s = {0.f,0.f,0.f,0.f};
    float l = 0.f;
    for (int sp=0;sp<16;++sp) {
      const int base = (h*16 + sp)*32 + row;
      const float4 v = *(const float4*)&o_part[(size_t)base*DH + c4*4];
      s.x += v.x; s.y += v.y; s.z += v.z; s.w += v.w;
      l += l_part[base];
    }
    const float inv = 1.f / l;
    f16x4 o;
    o[0] = (f16)(s.x*inv); o[1] = (f16)(s.y*inv);
    o[2] = (f16)(s.z*inv); o[3] = (f16)(s.w*inv);
    *(f16x4*)&att16[(size_t)row * DMOD + h*DH + c4*4] = o;
  }
}

extern "C" void kernel_launch(void* const* d_in, const int* in_sizes, int n_in,
                              void* d_out, int out_size, void* d_ws, size_t ws_size,
                              hipStream_t stream)
{
  const float* hs = (const float*)d_in[0];
  const float* Wq = (const float*)d_in[1];
  const float* bq = (const float*)d_in[2];
  const float* Wk = (const float*)d_in[3];
  const float* bk = (const float*)d_in[4];
  const float* Wv = (const float*)d_in[5];
  const float* bv = (const float*)d_in[6];
  const float* Wo = (const float*)d_in[7];
  const float* bo = (const float*)d_in[8];
  float* out = (float*)d_out;
  char* ws = (char*)d_ws;
  f16* h16  = (f16*)(ws + OFF_H16);
  f16* wt   = (f16*)(ws + OFF_WT);
  f16* q16  = (f16*)(ws + OFF_Q);
  f16* k16  = (f16*)(ws + OFF_K);
  f16* vt16 = (f16*)(ws + OFF_VT);
  f16* att16= (f16*)(ws + OFF_ATT);
  float* gqo = (float*)(ws + OFF_GQO);
  float* gql = (float*)(ws + OFF_GQL);

  prep_kernel<<<2112, 256, 0, stream>>>(hs, Wq, Wk, Wv, Wo, h16, wt);
  gemm_qkv<<<dim3(6,64,3), 256, 0, stream>>>(h16, wt, bq, bk, bv, q16, k16, vt16);
  band_attn<<<dim3(36,12), 256, 0, stream>>>(q16, k16, vt16, att16, gqo, gql);
  gq_merge<<<12, 256, 0, stream>>>(gqo, gql, att16);
  gemm_out<<<dim3(12,64), 256, 0, stream>>>(att16, wt + (size_t)3*DMOD*DMOD, bo, out);
}

// Round 6
// 170.830 us; speedup vs baseline: 1.0364x; 1.0364x over previous
//
#include <hip/hip_runtime.h>
#include <stdint.h>

#define S_LEN 4096
#define DMOD  768
#define NH    12
#define DH    64
#define GG    32
#define NEGBIG (-1e9f)

typedef _Float16 f16;
typedef f16 f16x8 __attribute__((ext_vector_type(8)));
typedef f16 f16x4 __attribute__((ext_vector_type(4)));
typedef float f32x4 __attribute__((ext_vector_type(4)));
typedef uint32_t u32;

// ---------- workspace offsets (bytes), all 256-aligned ----------
#define OFF_H16   ((size_t)0)
#define OFF_WT    ((size_t)6291456)
#define OFF_Q     ((size_t)11010048)
#define OFF_K     ((size_t)17301504)
#define OFF_VT    ((size_t)29884416)
#define OFF_ATT   ((size_t)36175872)
#define OFF_GQO   ((size_t)42467328)
#define OFF_GQL   ((size_t)44040192)

__device__ __forceinline__ void gld_lds16(const void* g, void* l) {
  typedef __attribute__((address_space(3))) u32 lds_u32;
  typedef __attribute__((address_space(1))) u32 glb_u32;
  __builtin_amdgcn_global_load_lds((glb_u32*)(uintptr_t)g,
                                   (lds_u32*)(u32)(uintptr_t)l, 16, 0, 0);
}

// ---------------- prep: weight transpose->f16 + hidden convert ----------------
__global__ __launch_bounds__(256) void prep_kernel(
    const float* __restrict__ hs,
    const float* __restrict__ Wq, const float* __restrict__ Wk,
    const float* __restrict__ Wv, const float* __restrict__ Wo,
    f16* __restrict__ h16, f16* __restrict__ wt)
{
  const int b = blockIdx.x;
  const int t = threadIdx.x;
  if (b < 576) {
    __shared__ float tile[64][65];
    const int w = b / 144, r2 = b % 144;
    const int n0 = (r2 % 12) * 64, k0 = (r2 / 12) * 64;
    const float* W = (w==0) ? Wq : (w==1) ? Wk : (w==2) ? Wv : Wo;
    f16* WT = wt + (size_t)w * DMOD * DMOD;
    #pragma unroll
    for (int rnd = 0; rnd < 4; ++rnd) {
      const int lin = rnd * 1024 + t * 4;
      const int r = lin >> 6, c = lin & 63;
      const float4 vv = *(const float4*)(W + (size_t)(k0 + r) * DMOD + n0 + c);
      tile[r][c+0] = vv.x; tile[r][c+1] = vv.y; tile[r][c+2] = vv.z; tile[r][c+3] = vv.w;
    }
    __syncthreads();
    #pragma unroll
    for (int rnd = 0; rnd < 2; ++rnd) {
      const int lin = rnd * 256 + t;
      const int n = lin >> 3, kc = (lin & 7) * 8;
      f16x8 o;
      #pragma unroll
      for (int j = 0; j < 8; ++j) o[j] = (f16)tile[kc + j][n];
      *(f16x8*)(WT + (size_t)(n0 + n) * DMOD + k0 + kc) = o;
    }
  } else {
    const size_t idx = (size_t)(b - 576) * 2048 + (size_t)t * 8;
    const float4 a = *(const float4*)(hs + idx);
    const float4 c = *(const float4*)(hs + idx + 4);
    f16x8 o;
    o[0]=(f16)a.x; o[1]=(f16)a.y; o[2]=(f16)a.z; o[3]=(f16)a.w;
    o[4]=(f16)c.x; o[5]=(f16)c.y; o[6]=(f16)c.z; o[7]=(f16)c.w;
    *(f16x8*)(h16 + idx) = o;
  }
}

// ---------------- QKV projection GEMM: 128x128 tiles, depth-2 prefetch ----------------
// 576 blocks, 48KB LDS (3 blocks/CU). Per iter: wait vmcnt(4) [4 outstanding =
// buf k+1's loads => buf k (issued 2 iters ago) landed], s_barrier, issue
// buf (k+2)%3 AFTER barrier (its readers finished compute k-1), compute buf k%3.
// z==2 (v) writes directly transposed (H,64,S): acc rows are 4 consecutive s.
__global__ __launch_bounds__(256) void gemm_qkv(
    const f16* __restrict__ A, const f16* __restrict__ wt,
    const float* __restrict__ bq, const float* __restrict__ bk, const float* __restrict__ bv,
    f16* __restrict__ q16, f16* __restrict__ k16, f16* __restrict__ vt16)
{
  __shared__ __align__(16) f16 At[3][4096];
  __shared__ __align__(16) f16 Bt[3][4096];
  const int z = blockIdx.z;
  const f16* Wt = wt + (size_t)z * DMOD * DMOD;
  const float* bias = (z==0) ? bq : (z==1) ? bk : bv;
  const float scale = (z==0) ? 0.125f : 1.0f;

  const int tid = threadIdx.x;
  const int lane = tid & 63, wid = tid >> 6;
  const int quad = lane >> 4, l15 = lane & 15;
  const int n0 = blockIdx.x * 128, m0 = blockIdx.y * 128;
  const int wm = (wid >> 1) * 64, wn = (wid & 1) * 64;

  f32x4 acc[4][4];
  #pragma unroll
  for (int i=0;i<4;++i)
    #pragma unroll
    for (int j=0;j<4;++j) acc[i][j] = (f32x4){0.f,0.f,0.f,0.f};

  const int lin0 = tid, lin1 = tid + 256;
  const int ar0 = ((lin0>>6)<<4) + (lin0&15), ac0 = ((lin0>>4)&3)*8;
  const int ar1 = ((lin1>>6)<<4) + (lin1&15), ac1 = ((lin1>>4)&3)*8;
  const f16* Ab = A  + (size_t)m0 * DMOD;
  const f16* Bb = Wt + (size_t)n0 * DMOD;

  // prologue: stage k-chunks 0,1 into buffers 0,1 (4 loads each per thread)
  #pragma unroll
  for (int p = 0; p < 2; ++p) {
    const int k0 = p * 32;
    gld_lds16(Ab + (size_t)ar0*DMOD + k0 + ac0, &At[p][lin0*8]);
    gld_lds16(Ab + (size_t)ar1*DMOD + k0 + ac1, &At[p][lin1*8]);
    gld_lds16(Bb + (size_t)ar0*DMOD + k0 + ac0, &Bt[p][lin0*8]);
    gld_lds16(Bb + (size_t)ar1*DMOD + k0 + ac1, &Bt[p][lin1*8]);
  }

  #pragma unroll 3
  for (int k = 0; k < 24; ++k) {
    const int cb = k % 3, ib = (k + 2) % 3;
    if (k < 23) {
      asm volatile("s_waitcnt vmcnt(4) lgkmcnt(0)" ::: "memory");
    } else {
      asm volatile("s_waitcnt vmcnt(0) lgkmcnt(0)" ::: "memory");
    }
    __builtin_amdgcn_s_barrier();
    if (k < 22) {
      const int k0 = (k + 2) * 32;
      gld_lds16(Ab + (size_t)ar0*DMOD + k0 + ac0, &At[ib][lin0*8]);
      gld_lds16(Ab + (size_t)ar1*DMOD + k0 + ac1, &At[ib][lin1*8]);
      gld_lds16(Bb + (size_t)ar0*DMOD + k0 + ac0, &Bt[ib][lin0*8]);
      gld_lds16(Bb + (size_t)ar1*DMOD + k0 + ac1, &Bt[ib][lin1*8]);
    }
    f16x8 af[4], bf[4];
    #pragma unroll
    for (int i=0;i<4;++i) {
      af[i] = *(const f16x8*)(&At[cb][((wm>>4)+i)*512 + lane*8]);
      bf[i] = *(const f16x8*)(&Bt[cb][((wn>>4)+i)*512 + lane*8]);
    }
    #pragma unroll
    for (int i=0;i<4;++i)
      #pragma unroll
      for (int j=0;j<4;++j)
        acc[i][j] = __builtin_amdgcn_mfma_f32_16x16x32_f16(af[i], bf[j], acc[i][j], 0, 0, 0);
  }

  if (z < 2) {
    f16* outp = (z==0) ? q16 : k16;
    #pragma unroll
    for (int j=0;j<4;++j) {
      const int col = n0 + wn + j*16 + l15;
      const float bcol = bias[col];
      const int h = col >> 6, d = col & 63;
      #pragma unroll
      for (int i=0;i<4;++i) {
        const int rbase = m0 + wm + i*16 + quad*4;
        f16* dst = outp + ((size_t)h * S_LEN + rbase) * DH + d;
        #pragma unroll
        for (int r=0;r<4;++r)
          dst[(size_t)r * DH] = (f16)((acc[i][j][r] + bcol) * scale);
      }
    }
  } else {
    #pragma unroll
    for (int j=0;j<4;++j) {
      const int col = n0 + wn + j*16 + l15;
      const float bcol = bias[col];
      const int h = col >> 6, d = col & 63;
      #pragma unroll
      for (int i=0;i<4;++i) {
        const int rbase = m0 + wm + i*16 + quad*4;
        f16x4 o;
        #pragma unroll
        for (int r=0;r<4;++r) o[r] = (f16)(acc[i][j][r] + bcol);
        *(f16x4*)(vt16 + ((size_t)h * DH + d) * S_LEN + rbase) = o;
      }
    }
  }
}

// ---------------- output GEMM: 64Mx64N tiles, depth-2 prefetch ----------------
// 768 blocks (3/CU), 24KB LDS (high TLP). Same pipeline discipline.
__global__ __launch_bounds__(256) void gemm_out(
    const f16* __restrict__ A, const f16* __restrict__ Wt,
    const float* __restrict__ bo, float* __restrict__ outp)
{
  __shared__ __align__(16) f16 At[3][2048];
  __shared__ __align__(16) f16 Bt[3][2048];
  const int tid = threadIdx.x;
  const int lane = tid & 63, wid = tid >> 6;
  const int quad = lane >> 4, l15 = lane & 15;
  const int n0 = blockIdx.x * 64, m0 = blockIdx.y * 64;
  const int wm = (wid >> 1) * 32, wn = (wid & 1) * 32;

  f32x4 acc[2][2];
  #pragma unroll
  for (int i=0;i<2;++i)
    #pragma unroll
    for (int j=0;j<2;++j) acc[i][j] = (f32x4){0.f,0.f,0.f,0.f};

  const int ar = ((tid>>6)<<4) + (tid&15), ac = ((tid>>4)&3)*8;
  const f16* Ab = A  + (size_t)m0 * DMOD;
  const f16* Bb = Wt + (size_t)n0 * DMOD;

  #pragma unroll
  for (int p = 0; p < 2; ++p) {
    const int k0 = p * 32;
    gld_lds16(Ab + (size_t)ar*DMOD + k0 + ac, &At[p][tid*8]);
    gld_lds16(Bb + (size_t)ar*DMOD + k0 + ac, &Bt[p][tid*8]);
  }

  #pragma unroll 3
  for (int k = 0; k < 24; ++k) {
    const int cb = k % 3, ib = (k + 2) % 3;
    if (k < 23) {
      asm volatile("s_waitcnt vmcnt(2) lgkmcnt(0)" ::: "memory");
    } else {
      asm volatile("s_waitcnt vmcnt(0) lgkmcnt(0)" ::: "memory");
    }
    __builtin_amdgcn_s_barrier();
    if (k < 22) {
      const int k0 = (k + 2) * 32;
      gld_lds16(Ab + (size_t)ar*DMOD + k0 + ac, &At[ib][tid*8]);
      gld_lds16(Bb + (size_t)ar*DMOD + k0 + ac, &Bt[ib][tid*8]);
    }
    f16x8 af[2], bf[2];
    #pragma unroll
    for (int i=0;i<2;++i) {
      af[i] = *(const f16x8*)(&At[cb][((wm>>4)+i)*512 + lane*8]);
      bf[i] = *(const f16x8*)(&Bt[cb][((wn>>4)+i)*512 + lane*8]);
    }
    #pragma unroll
    for (int i=0;i<2;++i)
      #pragma unroll
      for (int j=0;j<2;++j)
        acc[i][j] = __builtin_amdgcn_mfma_f32_16x16x32_f16(af[i], bf[j], acc[i][j], 0, 0, 0);
  }

  #pragma unroll
  for (int j=0;j<2;++j) {
    const int col = n0 + wn + j*16 + l15;
    const float bcol = bo[col];
    #pragma unroll
    for (int i=0;i<2;++i) {
      const int rbase = m0 + wm + i*16 + quad*4;
      #pragma unroll
      for (int r=0;r<4;++r)
        outp[(size_t)(rbase + r) * DMOD + col] = acc[i][j][r] + bcol;
    }
  }
}

// ---------------- banded attention + global-query partials, one WAVE per job ----------------
__global__ __launch_bounds__(256) void band_attn(
    const f16* __restrict__ q16, const f16* __restrict__ k16,
    const f16* __restrict__ vt16, f16* __restrict__ att16,
    float* __restrict__ o_part, float* __restrict__ l_part)
{
  __shared__ __align__(16) f16 Pbuf[4][1280];  // 32x40 f16 per wave
  const int h = blockIdx.y;
  const int tid = threadIdx.x, lane = tid & 63, wid = tid >> 6;
  const int quad = lane >> 4, l15 = lane & 15;
  f16* P = &Pbuf[wid][0];

  const int bx = blockIdx.x;
  const bool is_gq = (bx >= 32);
  int gr0 = 0, sp = 0, tcount;
  if (is_gq) {
    sp = (bx - 32) * 4 + wid;
    tcount = 8;
  } else {
    const int sub = bx * 4 + wid;
    if (sub == 0) return;                      // rows 0..31 handled by gq path
    gr0 = sub * 32;
    tcount = 10;
  }

  const f16* qh = q16 + (size_t)h * S_LEN * DH;
  const f16* kh = k16 + (size_t)h * S_LEN * DH;
  const f16* vh = vt16 + (size_t)h * DH * S_LEN;

  f16x8 aq[2][2];
  #pragma unroll
  for (int mt=0;mt<2;++mt)
    #pragma unroll
    for (int ks=0;ks<2;++ks)
      aq[mt][ks] = *(const f16x8*)(qh + (size_t)(gr0 + mt*16 + l15)*DH + ks*32 + quad*8);

  f32x4 accO[2][4];
  float lacc[2][4];
  #pragma unroll
  for (int mt=0;mt<2;++mt) {
    #pragma unroll
    for (int n=0;n<4;++n) accO[mt][n] = (f32x4){0.f,0.f,0.f,0.f};
    #pragma unroll
    for (int r=0;r<4;++r) lacc[mt][r] = 0.f;
  }

  for (int t = 0; t < tcount; ++t) {
    int j0;
    if (is_gq) {
      j0 = sp*256 + t*32;
    } else if (t > 0) {
      j0 = gr0 - 128 + (t-1)*32;
      if (j0 <= 0 || j0 >= S_LEN) continue;    // whole-tile j-clip (always aligned)
    } else {
      j0 = 0;                                  // 32 global key columns
    }
    f16x8 bk[2][2];
    #pragma unroll
    for (int nt=0;nt<2;++nt) {
      const int key = j0 + nt*16 + l15;
      #pragma unroll
      for (int ks=0;ks<2;++ks)
        bk[nt][ks] = *(const f16x8*)(kh + (size_t)key*DH + ks*32 + quad*8);
    }
    f32x4 sc[2][2];
    #pragma unroll
    for (int mt=0;mt<2;++mt)
      #pragma unroll
      for (int nt=0;nt<2;++nt) {
        f32x4 s = __builtin_amdgcn_mfma_f32_16x16x32_f16(aq[mt][0], bk[nt][0],
                                                         (f32x4){0.f,0.f,0.f,0.f}, 0,0,0);
        sc[mt][nt] = __builtin_amdgcn_mfma_f32_16x16x32_f16(aq[mt][1], bk[nt][1], s, 0,0,0);
      }
    if (!is_gq && (t == 1 || t == 9)) {        // only edge band tiles need masks
      #pragma unroll
      for (int nt=0;nt<2;++nt)
        #pragma unroll
        for (int mt=0;mt<2;++mt)
          #pragma unroll
          for (int r=0;r<4;++r) {
            const int e = (nt*16 + l15) - (mt*16 + quad*4 + r);
            const bool ok = (t == 1) ? (e >= 0) : (e <= 0);
            if (!ok) sc[mt][nt][r] = NEGBIG;
          }
    }
    #pragma unroll
    for (int mt=0;mt<2;++mt)
      #pragma unroll
      for (int r=0;r<4;++r) {
        sc[mt][0][r] = __expf(sc[mt][0][r]);
        sc[mt][1][r] = __expf(sc[mt][1][r]);
        lacc[mt][r] += sc[mt][0][r] + sc[mt][1][r];
      }
    // P: C-layout -> LDS -> A-layout (per-wave scratch; in-order DS queue)
    #pragma unroll
    for (int mt=0;mt<2;++mt)
      #pragma unroll
      for (int nt=0;nt<2;++nt)
        #pragma unroll
        for (int r=0;r<4;++r)
          P[(mt*16 + quad*4 + r)*40 + nt*16 + l15] = (f16)sc[mt][nt][r];
    asm volatile("s_waitcnt lgkmcnt(0)" ::: "memory");
    f16x8 ap[2];
    #pragma unroll
    for (int mt=0;mt<2;++mt)
      ap[mt] = *(const f16x8*)(P + (mt*16 + l15)*40 + quad*8);
    #pragma unroll
    for (int n=0;n<4;++n) {
      const f16x8 bv = *(const f16x8*)(vh + (size_t)(n*16 + l15)*S_LEN + j0 + quad*8);
      #pragma unroll
      for (int mt=0;mt<2;++mt)
        accO[mt][n] = __builtin_amdgcn_mfma_f32_16x16x32_f16(ap[mt], bv, accO[mt][n], 0,0,0);
    }
  }

  // in-wave reduce of l partials across the 16 column-lanes
  #pragma unroll
  for (int mt=0;mt<2;++mt)
    #pragma unroll
    for (int r=0;r<4;++r) {
      float v = lacc[mt][r];
      v += __shfl_xor(v, 1, 64);
      v += __shfl_xor(v, 2, 64);
      v += __shfl_xor(v, 4, 64);
      v += __shfl_xor(v, 8, 64);
      lacc[mt][r] = v;
    }

  if (is_gq) {
    const int base = (h*16 + sp)*32;
    #pragma unroll
    for (int mt=0;mt<2;++mt)
      #pragma unroll
      for (int r=0;r<4;++r) {
        const int row = mt*16 + quad*4 + r;
        if (l15 == 0) l_part[base+row] = lacc[mt][r];
        #pragma unroll
        for (int n=0;n<4;++n)
          o_part[(size_t)(base+row)*DH + n*16 + l15] = accO[mt][n][r];
      }
  } else {
    #pragma unroll
    for (int mt=0;mt<2;++mt)
      #pragma unroll
      for (int r=0;r<4;++r) {
        const float inv = 1.f / lacc[mt][r];
        const int s = gr0 + mt*16 + quad*4 + r;
        #pragma unroll
        for (int n=0;n<4;++n)
          att16[(size_t)s * DMOD + h*DH + n*16 + l15] = (f16)(accO[mt][n][r] * inv);
      }
  }
}

__global__ __launch_bounds__(256) void gq_merge(
    const float* __restrict__ o_part, const float* __restrict__ l_part,
    f16* __restrict__ att16)
{
  const int h = blockIdx.x;
  const int t = threadIdx.x;
  for (int u = t; u < 512; u += 256) {
    const int row = u >> 4, c4 = u & 15;
    float4 s = {0.f,0.f,0.f,0.f};
    float l = 0.f;
    for (int sp=0;sp<16;++sp) {
      const int base = (h*16 + sp)*32 + row;
      const float4 v = *(const float4*)&o_part[(size_t)base*DH + c4*4];
      s.x += v.x; s.y += v.y; s.z += v.z; s.w += v.w;
      l += l_part[base];
    }
    const float inv = 1.f / l;
    f16x4 o;
    o[0] = (f16)(s.x*inv); o[1] = (f16)(s.y*inv);
    o[2] = (f16)(s.z*inv); o[3] = (f16)(s.w*inv);
    *(f16x4*)&att16[(size_t)row * DMOD + h*DH + c4*4] = o;
  }
}

extern "C" void kernel_launch(void* const* d_in, const int* in_sizes, int n_in,
                              void* d_out, int out_size, void* d_ws, size_t ws_size,
                              hipStream_t stream)
{
  const float* hs = (const float*)d_in[0];
  const float* Wq = (const float*)d_in[1];
  const float* bq = (const float*)d_in[2];
  const float* Wk = (const float*)d_in[3];
  const float* bk = (const float*)d_in[4];
  const float* Wv = (const float*)d_in[5];
  const float* bv = (const float*)d_in[6];
  const float* Wo = (const float*)d_in[7];
  const float* bo = (const float*)d_in[8];
  float* out = (float*)d_out;
  char* ws = (char*)d_ws;
  f16* h16  = (f16*)(ws + OFF_H16);
  f16* wt   = (f16*)(ws + OFF_WT);
  f16* q16  = (f16*)(ws + OFF_Q);
  f16* k16  = (f16*)(ws + OFF_K);
  f16* vt16 = (f16*)(ws + OFF_VT);
  f16* att16= (f16*)(ws + OFF_ATT);
  float* gqo = (float*)(ws + OFF_GQO);
  float* gql = (float*)(ws + OFF_GQL);

  prep_kernel<<<2112, 256, 0, stream>>>(hs, Wq, Wk, Wv, Wo, h16, wt);
  gemm_qkv<<<dim3(6,32,3), 256, 0, stream>>>(h16, wt, bq, bk, bv, q16, k16, vt16);
  band_attn<<<dim3(36,12), 256, 0, stream>>>(q16, k16, vt16, att16, gqo, gql);
  gq_merge<<<12, 256, 0, stream>>>(gqo, gql, att16);
  gemm_out<<<dim3(12,64), 256, 0, stream>>>(att16, wt + (size_t)3*DMOD*DMOD, bo, out);
}